// Round 3
// baseline (53.751 us; speedup 1.0000x reference)
//
#include <hip/hip_runtime.h>

// HungarianMatcher cost matrix: C[n,m] = 5*L1(boxes) + 2*focal_class + 2*(-GIoU)
// Shapes: logits [N=16000, NC=256], pred_boxes [N,4] (cxcywh),
//         tgt_labels [M=1600], tgt_boxes [M,4] (cxcywh), out [N, M] fp32.

constexpr float ALPHAc  = 0.25f;
constexpr float EPSc    = 1e-8f;
constexpr float W_CLASS = 2.0f;
constexpr float W_BBOX  = 5.0f;
constexpr float W_GIOU  = 2.0f;

constexpr int NC  = 256;   // classes (== blockDim.x)
constexpr int NT  = 256;   // threads per block
constexpr int RPB = 10;    // rows per block

__global__ __launch_bounds__(NT)
void hungarian_cost_kernel(const float* __restrict__ logits,   // [N, NC]
                           const float* __restrict__ pboxes,   // [N, 4]
                           const int*   __restrict__ tlabels,  // [M]
                           const float* __restrict__ tboxes,   // [M, 4]
                           float*       __restrict__ out,      // [N, M]
                           int N, int M)
{
    const int t  = threadIdx.x;
    const int n0 = blockIdx.x * RPB;

    __shared__ float fc[2][NC];   // focal class cost, double-buffered per row

    // Each thread owns up to 2 float4-output-groups: group g covers
    // m = 4*(g*NT + t) .. +3. Cache target boxes (cxcywh) + ids in registers.
    const int F4 = M >> 2;                 // number of float4 groups (400)
    float tcx[2][4], tcy[2][4], tw_[2][4], th_[2][4];
    int   tcls[2][4];
    bool  gvalid[2];
#pragma unroll
    for (int g = 0; g < 2; ++g) {
        const int f = g * NT + t;
        gvalid[g] = (f < F4);
        if (gvalid[g]) {
#pragma unroll
            for (int k = 0; k < 4; ++k) {
                const int m = f * 4 + k;
                const float4 b = reinterpret_cast<const float4*>(tboxes)[m];
                tcx[g][k] = b.x; tcy[g][k] = b.y; tw_[g][k] = b.z; th_[g][k] = b.w;
                int c = tlabels[m];
                c = c < 0 ? 0 : (c > NC - 1 ? NC - 1 : c);
                tcls[g][k] = c;
            }
        } else {
#pragma unroll
            for (int k = 0; k < 4; ++k) {
                tcx[g][k] = 0.f; tcy[g][k] = 0.f; tw_[g][k] = 0.f; th_[g][k] = 0.f;
                tcls[g][k] = 0;
            }
        }
    }

    int buf = 0;
    for (int r = 0; r < RPB; ++r) {
        const int n = n0 + r;
        if (n >= N) break;  // block-uniform

        // Focal class cost for class t of row n (each logit read once, chip-wide).
        {
            const float x = logits[(size_t)n * NC + t];
            const float e = __expf(-x);
            const float p = 1.0f / (1.0f + e);
            const float q = 1.0f - p;
            const float pos = ALPHAc * q * q * (-__logf(p + EPSc));
            const float neg = (1.0f - ALPHAc) * p * p * (-__logf(q + EPSc));
            fc[buf][t] = pos - neg;
        }
        __syncthreads();

        // Pred box for this row (broadcast load).
        const float4 pb = reinterpret_cast<const float4*>(pboxes)[n];
        const float pax0 = pb.x - 0.5f * pb.z, pay0 = pb.y - 0.5f * pb.w;
        const float pax1 = pb.x + 0.5f * pb.z, pay1 = pb.y + 0.5f * pb.w;
        const float parea = pb.z * pb.w;

        float* __restrict__ orow = out + (size_t)n * M;

#pragma unroll
        for (int g = 0; g < 2; ++g) {
            if (!gvalid[g]) continue;
            float res[4];
#pragma unroll
            for (int k = 0; k < 4; ++k) {
                const float bcx = tcx[g][k], bcy = tcy[g][k];
                const float bw = tw_[g][k],  bh = th_[g][k];

                // L1 cdist on cxcywh
                const float cb = fabsf(pb.x - bcx) + fabsf(pb.y - bcy)
                               + fabsf(pb.z - bw)  + fabsf(pb.w - bh);

                // cxcywh -> xyxy
                const float bx0 = bcx - 0.5f * bw, by0 = bcy - 0.5f * bh;
                const float bx1 = bcx + 0.5f * bw, by1 = bcy + 0.5f * bh;
                const float barea = bw * bh;

                // intersection / union
                const float ix0 = fmaxf(pax0, bx0), iy0 = fmaxf(pay0, by0);
                const float ix1 = fminf(pax1, bx1), iy1 = fminf(pay1, by1);
                const float iw = fmaxf(ix1 - ix0, 0.f), ih = fmaxf(iy1 - iy0, 0.f);
                const float inter = iw * ih;
                const float uni = parea + barea - inter;

                // enclosing box
                const float cx0 = fminf(pax0, bx0), cy0 = fminf(pay0, by0);
                const float cx1 = fmaxf(pax1, bx1), cy1 = fmaxf(pay1, by1);
                const float cw = fmaxf(cx1 - cx0, 0.f), ch = fmaxf(cy1 - cy0, 0.f);
                const float carea = cw * ch;

                const float iou  = inter * __builtin_amdgcn_rcpf(uni);
                const float giou = iou - (carea - uni) * __builtin_amdgcn_rcpf(carea);

                const float cc = fc[buf][tcls[g][k]];
                res[k] = W_BBOX * cb + W_CLASS * cc - W_GIOU * giou;
            }
            const int f = g * NT + t;
            float4 v; v.x = res[0]; v.y = res[1]; v.z = res[2]; v.w = res[3];
            reinterpret_cast<float4*>(orow)[f] = v;
        }
        buf ^= 1;
        // Double buffer: next row writes the other fc buffer; the row after
        // that re-writes this one only after two intervening barriers. Safe.
    }
}

extern "C" void kernel_launch(void* const* d_in, const int* in_sizes, int n_in,
                              void* d_out, int out_size, void* d_ws, size_t ws_size,
                              hipStream_t stream) {
    const float* logits  = (const float*)d_in[0];   // [16,1000,256] fp32
    const float* pboxes  = (const float*)d_in[1];   // [16,1000,4]  fp32
    const int*   tlabels = (const int*)d_in[2];     // [1600] int
    const float* tboxes  = (const float*)d_in[3];   // [1600,4] fp32

    float* out = (float*)d_out;

    const int N = in_sizes[1] / 4;   // 16000 pred rows
    const int M = in_sizes[2];       // 1600 targets

    const int nblocks = (N + RPB - 1) / RPB;   // 1600
    hipLaunchKernelGGL(hungarian_cost_kernel, dim3(nblocks), dim3(NT), 0, stream,
                       logits, pboxes, tlabels, tboxes, out, N, M);
}

// Round 4
// 47.018 us; speedup vs baseline: 1.1432x; 1.1432x over previous
//
#include <hip/hip_runtime.h>

// HungarianMatcher cost matrix: C[n,m] = 5*L1(boxes) + 2*focal_class - 2*GIoU
// logits [N=16000, NC=256] f32, pred_boxes [N,4] cxcywh f32,
// tgt_labels [M=1600] i32, tgt_boxes [M,4] cxcywh f32, out [N,M] f32.

constexpr float ALPHAc = 0.25f;
constexpr float EPSc   = 1e-8f;

constexpr int NC    = 256;  // classes (== blockDim.x)
constexpr int NT    = 256;  // threads per block
constexpr int RPB   = 10;   // rows per block
constexpr int MAXSP = 4;    // max scalar phases (covers M - 4*NT elements)

struct TBox { float x0, y0, x1, y1, area; int cls; };

__device__ __forceinline__ TBox load_tgt(const float4* __restrict__ tb4,
                                         const int* __restrict__ tlabels, int m) {
    const float4 b = tb4[m];
    TBox r;
    r.x0 = fmaf(-0.5f, b.z, b.x);
    r.y0 = fmaf(-0.5f, b.w, b.y);
    r.x1 = fmaf( 0.5f, b.z, b.x);
    r.y1 = fmaf( 0.5f, b.w, b.y);
    r.area = b.z * b.w;
    int c = tlabels[m];
    c = c < 0 ? 0 : (c > NC - 1 ? NC - 1 : c);
    r.cls = c;
    return r;
}

// 5*L1 + 2*fc - 2*GIoU, with GIoU = inter/uni + uni/carea - 1.
// L1 on cxcywh from xyxy regs: |dcx|+|dw| = 0.5|u0+u1| + |u1-u0|, u=b-p per corner.
// Enclosing w/h need no clamp: all boxes have w,h >= 0.
__device__ __forceinline__ float cost_elem(float px0, float py0, float px1, float py1,
                                           float parea, const TBox& b, float fcv) {
    const float u0 = b.x0 - px0, u1 = b.x1 - px1;
    const float v0 = b.y0 - py0, v1 = b.y1 - py1;
    const float l1 = fmaf(0.5f, fabsf(u0 + u1), fabsf(u1 - u0))
                   + fmaf(0.5f, fabsf(v0 + v1), fabsf(v1 - v0));
    const float iw = fmaxf(fminf(px1, b.x1) - fmaxf(px0, b.x0), 0.0f);
    const float ih = fmaxf(fminf(py1, b.y1) - fmaxf(py0, b.y0), 0.0f);
    const float inter = iw * ih;
    const float uni   = parea + b.area - inter;
    const float cw = fmaxf(px1, b.x1) - fminf(px0, b.x0);
    const float ch = fmaxf(py1, b.y1) - fminf(py0, b.y0);
    const float carea = cw * ch;
    const float m1 = inter * __builtin_amdgcn_rcpf(uni);
    const float m2 = uni   * __builtin_amdgcn_rcpf(carea);
    return fmaf(-2.0f, m1 + m2, fmaf(5.0f, l1, fmaf(2.0f, fcv, 2.0f)));
}

__global__ __launch_bounds__(NT)
void hungarian_cost_kernel(const float* __restrict__ logits,
                           const float* __restrict__ pboxes,
                           const int*   __restrict__ tlabels,
                           const float* __restrict__ tboxes,
                           float*       __restrict__ out,
                           int N, int M)
{
    const int t  = threadIdx.x;
    const int n0 = blockIdx.x * RPB;
    const float4* tb4p = reinterpret_cast<const float4*>(tboxes);

    __shared__ float fc[RPB][NC];   // focal class cost for all RPB rows

    // Focal for all rows upfront (each logit read once chip-wide), ONE barrier.
#pragma unroll
    for (int r = 0; r < RPB; ++r) {
        const int n = n0 + r;
        float v = 0.0f;
        if (n < N) {
            const float x = logits[(size_t)n * NC + t];
            const float p = __builtin_amdgcn_rcpf(1.0f + __expf(-x));
            const float q = 1.0f - p;
            const float pos = ALPHAc * q * q * (-__logf(p + EPSc));
            const float neg = (1.0f - ALPHAc) * p * p * (-__logf(q + EPSc));
            v = pos - neg;
        }
        fc[r][t] = v;
    }
    __syncthreads();

    // Register-cache targets, pre-converted to xyxy+area.
    // Layout: float4 groups [0, min(NT, M/4)) -> thread t owns group t (4 elems),
    // then scalar phases of NT elements cover the remainder (99% lane util).
    const int ng4 = M >> 2;
    const bool g4v = (t < ng4);
    TBox tg[4];
    if (g4v) {
#pragma unroll
        for (int k = 0; k < 4; ++k) tg[k] = load_tgt(tb4p, tlabels, 4 * t + k);
    }
    const int sbase0 = 4 * (ng4 < NT ? ng4 : NT);
    TBox ts[MAXSP];
    bool sv[MAXSP];
#pragma unroll
    for (int p = 0; p < MAXSP; ++p) {
        const int e = sbase0 + p * NT + t;
        sv[p] = (e < M);
        if (sv[p]) ts[p] = load_tgt(tb4p, tlabels, e);
        else { ts[p].x0 = ts[p].y0 = ts[p].x1 = ts[p].y1 = ts[p].area = 0.0f; ts[p].cls = 0; }
    }

    for (int r = 0; r < RPB; ++r) {
        const int n = n0 + r;
        if (n >= N) break;  // block-uniform
        const float4 pb = reinterpret_cast<const float4*>(pboxes)[n];
        const float px0 = fmaf(-0.5f, pb.z, pb.x);
        const float py0 = fmaf(-0.5f, pb.w, pb.y);
        const float px1 = fmaf( 0.5f, pb.z, pb.x);
        const float py1 = fmaf( 0.5f, pb.w, pb.y);
        const float parea = pb.z * pb.w;
        float* __restrict__ orow = out + (size_t)n * M;
        const float* __restrict__ frow = fc[r];

        // Hoist the LDS class-cost gathers so they batch under one lgkmcnt.
        float fg[4], fs[MAXSP];
        if (g4v) {
#pragma unroll
            for (int k = 0; k < 4; ++k) fg[k] = frow[tg[k].cls];
        }
#pragma unroll
        for (int p = 0; p < MAXSP; ++p) fs[p] = sv[p] ? frow[ts[p].cls] : 0.0f;

        if (g4v) {
            float4 res;
            res.x = cost_elem(px0, py0, px1, py1, parea, tg[0], fg[0]);
            res.y = cost_elem(px0, py0, px1, py1, parea, tg[1], fg[1]);
            res.z = cost_elem(px0, py0, px1, py1, parea, tg[2], fg[2]);
            res.w = cost_elem(px0, py0, px1, py1, parea, tg[3], fg[3]);
            reinterpret_cast<float4*>(orow)[t] = res;
        }
#pragma unroll
        for (int p = 0; p < MAXSP; ++p) {
            if (sv[p])
                orow[sbase0 + p * NT + t] =
                    cost_elem(px0, py0, px1, py1, parea, ts[p], fs[p]);
        }
    }
}

extern "C" void kernel_launch(void* const* d_in, const int* in_sizes, int n_in,
                              void* d_out, int out_size, void* d_ws, size_t ws_size,
                              hipStream_t stream) {
    const float* logits  = (const float*)d_in[0];   // [16,1000,256] f32
    const float* pboxes  = (const float*)d_in[1];   // [16,1000,4]  f32
    const int*   tlabels = (const int*)d_in[2];     // [1600] i32
    const float* tboxes  = (const float*)d_in[3];   // [1600,4] f32

    float* out = (float*)d_out;

    const int N = in_sizes[1] / 4;   // 16000 pred rows
    const int M = in_sizes[2];       // 1600 targets

    const int nblocks = (N + RPB - 1) / RPB;   // 1600
    hipLaunchKernelGGL(hungarian_cost_kernel, dim3(nblocks), dim3(NT), 0, stream,
                       logits, pboxes, tlabels, tboxes, out, N, M);
}

// Round 5
// 39.988 us; speedup vs baseline: 1.3442x; 1.1758x over previous
//
#include <hip/hip_runtime.h>

// HungarianMatcher cost matrix: C[n,m] = 5*L1(boxes) + 2*focal_class - 2*GIoU
// logits [N=16000, NC=256] f32, pred_boxes [N,4] cxcywh f32,
// tgt_labels [M=1600] i32, tgt_boxes [M,4] cxcywh f32, out [N,M] f32.

constexpr float ALPHAc = 0.25f;
constexpr float EPSc   = 1e-8f;

constexpr int NC  = 256;  // classes (== blockDim.x)
constexpr int NT  = 256;  // threads per block
constexpr int RPB = 8;    // rows per block (16000 % 8 == 0 -> 2000 blocks)

struct TBox { float x0, y0, x1, y1, area; int off; };  // off = cls*4 (fc byte offset)

__device__ __forceinline__ TBox make_tgt(float4 b, int c) {
    TBox r;
    r.x0 = fmaf(-0.5f, b.z, b.x);
    r.y0 = fmaf(-0.5f, b.w, b.y);
    r.x1 = fmaf( 0.5f, b.z, b.x);
    r.y1 = fmaf( 0.5f, b.w, b.y);
    r.area = b.z * b.w;
    c = c < 0 ? 0 : (c > NC - 1 ? NC - 1 : c);
    r.off = c << 2;
    return r;
}

__device__ __forceinline__ float lds_gather(const float* frow, int byteoff) {
    return *(const float*)((const char*)frow + byteoff);
}

// res = 5*L1 + (2*fc+2) - 2*(inter/uni + uni/carea)
//  L1 on cxcywh from xyxy: 0.5|u0+u1| + |u1-u0| per axis (u = b-p per corner).
//  Enclosing width via identity: max(p1,b1)-min(p0,b0) = pw + bw - (min(p1,b1)-max(p0,b0))
//  and bw = pw + (u1-u0)  ->  cw = 2pw + du - iwr   (reuses L1 temporaries).
//  Single reciprocal: inter/uni + uni/carea = (uni^2 + inter*carea) / (uni*carea).
__device__ __forceinline__ float cost_elem(float px0, float py0, float px1, float py1,
                                           float parea, float pw2, float ph2,
                                           const TBox& b, float fcp) {
    const float u0 = b.x0 - px0, u1 = b.x1 - px1;
    const float v0 = b.y0 - py0, v1 = b.y1 - py1;
    const float du = u1 - u0,    dv = v1 - v0;
    const float l1 = fmaf(0.5f, fabsf(u0 + u1), fabsf(du))
                   + fmaf(0.5f, fabsf(v0 + v1), fabsf(dv));
    const float ix0 = fmaxf(px0, b.x0), ix1 = fminf(px1, b.x1);
    const float iy0 = fmaxf(py0, b.y0), iy1 = fminf(py1, b.y1);
    const float iwr = ix1 - ix0, ihr = iy1 - iy0;
    const float inter = fmaxf(iwr, 0.0f) * fmaxf(ihr, 0.0f);
    const float uni   = (parea + b.area) - inter;
    const float cw = (pw2 + du) - iwr;
    const float ch = (ph2 + dv) - ihr;
    const float carea = cw * ch;
    const float num = fmaf(uni, uni, inter * carea);
    const float mm  = num * __builtin_amdgcn_rcpf(uni * carea);
    return fmaf(-2.0f, mm, fmaf(5.0f, l1, fcp));
}

__global__ __launch_bounds__(NT)
void hungarian_cost_kernel(const float* __restrict__ logits,
                           const float* __restrict__ pboxes,
                           const int*   __restrict__ tlabels,
                           const float* __restrict__ tboxes,
                           float*       __restrict__ out,
                           int N, int M)
{
    const int t  = threadIdx.x;
    const int n0 = blockIdx.x * RPB;
    if (n0 >= N) return;
    const int rows = (N - n0 < RPB) ? (N - n0) : RPB;

    __shared__ float  fc[RPB][NC];   // 2*focal+2, per row per class
    __shared__ float4 pbs[RPB];      // pred boxes for this block's rows

    // ---- Prologue: focal costs for all rows + pred-box staging. ONE barrier. ----
#pragma unroll
    for (int r = 0; r < RPB; ++r) {
        if (r < rows) {
            const float x = logits[(size_t)(n0 + r) * NC + t];
            const float p = __builtin_amdgcn_rcpf(1.0f + __expf(-x));
            const float q = 1.0f - p;
            const float pos = ALPHAc * q * q * (-__logf(p + EPSc));
            const float neg = (1.0f - ALPHAc) * p * p * (-__logf(q + EPSc));
            fc[r][t] = fmaf(2.0f, pos - neg, 2.0f);
        }
    }
    if (t < rows) pbs[t] = reinterpret_cast<const float4*>(pboxes)[n0 + t];

    // ---- Register-cache targets (xyxy + area + class byte-offset). ----
    // m-layout for 100% lane util: nA float4 groups, nB float2 groups, nC scalars.
    // M=1600: 256*4 + 256*2 + 64*1 (scalar phase = exactly wave 0).
    const float4* tb4 = reinterpret_cast<const float4*>(tboxes);
    const int nA    = (M >> 2) < NT ? (M >> 2) : NT;
    const int baseB = 4 * nA;
    const int nB    = ((M - baseB) >> 1) < NT ? ((M - baseB) >> 1) : NT;
    const int baseC = baseB + 2 * nB;
    const int nC    = M - baseC;

    const bool aV = t < nA;
    const bool bV = t < nB;
    const bool cV = t < nC;

    TBox ta[4], tb_[2], tc;
    if (aV) {
        const int4 c4 = reinterpret_cast<const int4*>(tlabels)[t];
        ta[0] = make_tgt(tb4[4 * t + 0], c4.x);
        ta[1] = make_tgt(tb4[4 * t + 1], c4.y);
        ta[2] = make_tgt(tb4[4 * t + 2], c4.z);
        ta[3] = make_tgt(tb4[4 * t + 3], c4.w);
    }
    if (bV) {
        const int2 c2 = reinterpret_cast<const int2*>(tlabels + baseB)[t];
        tb_[0] = make_tgt(tb4[baseB + 2 * t + 0], c2.x);
        tb_[1] = make_tgt(tb4[baseB + 2 * t + 1], c2.y);
    }
    if (cV) tc = make_tgt(tb4[baseC + t], tlabels[baseC + t]);

    __syncthreads();

    // ---- Row loop: LDS + VALU + stores only (no global loads -> no vmcnt
    //      wait ever blocks on the previous row's stores). Fully unrolled so
    //      fc gathers become ds_read with immediate row offsets. ----
#pragma unroll
    for (int r = 0; r < RPB; ++r) {
        if (r >= rows) break;  // block-uniform
        const float4 pb = pbs[r];
        const float px0 = fmaf(-0.5f, pb.z, pb.x);
        const float py0 = fmaf(-0.5f, pb.w, pb.y);
        const float px1 = fmaf( 0.5f, pb.z, pb.x);
        const float py1 = fmaf( 0.5f, pb.w, pb.y);
        const float parea = pb.z * pb.w;
        const float pw2 = pb.z + pb.z;
        const float ph2 = pb.w + pb.w;
        const float* frow = fc[r];
        float* orow = out + (size_t)(n0 + r) * M;

        if (aV) {
            float f0 = lds_gather(frow, ta[0].off);
            float f1 = lds_gather(frow, ta[1].off);
            float f2 = lds_gather(frow, ta[2].off);
            float f3 = lds_gather(frow, ta[3].off);
            float4 res;
            res.x = cost_elem(px0, py0, px1, py1, parea, pw2, ph2, ta[0], f0);
            res.y = cost_elem(px0, py0, px1, py1, parea, pw2, ph2, ta[1], f1);
            res.z = cost_elem(px0, py0, px1, py1, parea, pw2, ph2, ta[2], f2);
            res.w = cost_elem(px0, py0, px1, py1, parea, pw2, ph2, ta[3], f3);
            reinterpret_cast<float4*>(orow)[t] = res;
        }
        if (bV) {
            float f0 = lds_gather(frow, tb_[0].off);
            float f1 = lds_gather(frow, tb_[1].off);
            float2 res;
            res.x = cost_elem(px0, py0, px1, py1, parea, pw2, ph2, tb_[0], f0);
            res.y = cost_elem(px0, py0, px1, py1, parea, pw2, ph2, tb_[1], f1);
            reinterpret_cast<float2*>(orow + baseB)[t] = res;
        }
        if (cV) {
            float f0 = lds_gather(frow, tc.off);
            orow[baseC + t] = cost_elem(px0, py0, px1, py1, parea, pw2, ph2, tc, f0);
        }
    }
}

extern "C" void kernel_launch(void* const* d_in, const int* in_sizes, int n_in,
                              void* d_out, int out_size, void* d_ws, size_t ws_size,
                              hipStream_t stream) {
    const float* logits  = (const float*)d_in[0];   // [16,1000,256] f32
    const float* pboxes  = (const float*)d_in[1];   // [16,1000,4]  f32
    const int*   tlabels = (const int*)d_in[2];     // [1600] i32
    const float* tboxes  = (const float*)d_in[3];   // [1600,4] f32

    float* out = (float*)d_out;

    const int N = in_sizes[1] / 4;   // 16000 pred rows
    const int M = in_sizes[2];       // 1600 targets

    const int nblocks = (N + RPB - 1) / RPB;   // 2000
    hipLaunchKernelGGL(hungarian_cost_kernel, dim3(nblocks), dim3(NT), 0, stream,
                       logits, pboxes, tlabels, tboxes, out, N, M);
}

// Round 7
// 33.172 us; speedup vs baseline: 1.6204x; 1.2055x over previous
//
#include <hip/hip_runtime.h>

// HungarianMatcher cost matrix: C[n,m] = 5*L1(boxes) + 2*focal_class - 2*GIoU
// logits [N=16000, NC=256] f32, pred_boxes [N,4] cxcywh f32,
// tgt_labels [M=1600] i32, tgt_boxes [M,4] cxcywh f32, out [N,M] f32.

constexpr float ALPHAc = 0.25f;
constexpr float EPSc   = 1e-8f;

constexpr int NC  = 256;  // classes (== blockDim.x)
constexpr int NT  = 256;  // threads per block
constexpr int RPB = 8;    // rows per block (16000 % 8 == 0 -> 2000 blocks)

// clang native vectors: __builtin_nontemporal_store accepts these (HIP_vector_type
// float4/float2 are structs and are rejected).
typedef float f32x4 __attribute__((ext_vector_type(4)));
typedef float f32x2 __attribute__((ext_vector_type(2)));

struct TBox { float x0, y0, x1, y1, area; };

__device__ __forceinline__ TBox make_box(float4 b) {
    TBox r;
    r.x0 = fmaf(-0.5f, b.z, b.x);
    r.y0 = fmaf(-0.5f, b.w, b.y);
    r.x1 = fmaf( 0.5f, b.z, b.x);
    r.y1 = fmaf( 0.5f, b.w, b.y);
    r.area = b.z * b.w;
    return r;
}

// Base pointer into fc[0][cls]; row r's value is base[r*NC] -> ds_read_b32
// with immediate offset r*1024 (no per-row address math).
__device__ __forceinline__ const float* fc_base(const float* fc0, int c) {
    c = c < 0 ? 0 : (c > NC - 1 ? NC - 1 : c);
    return fc0 + c;
}

// res = 5*L1 + (2*fc+2) - 2*(inter/uni + uni/carea)
//  L1 on cxcywh from xyxy: 0.5|u0+u1| + |u1-u0| per axis (u = b-p per corner).
//  Enclosing width identity: cw = 2pw + (u1-u0) - iwr (reuses L1 temporaries).
//  Single reciprocal: inter/uni + uni/carea = (uni^2 + inter*carea)/(uni*carea).
__device__ __forceinline__ float cost_elem(float px0, float py0, float px1, float py1,
                                           float parea, float pw2, float ph2,
                                           const TBox& b, float fcp) {
    const float u0 = b.x0 - px0, u1 = b.x1 - px1;
    const float v0 = b.y0 - py0, v1 = b.y1 - py1;
    const float du = u1 - u0,    dv = v1 - v0;
    const float l1 = fmaf(0.5f, fabsf(u0 + u1), fabsf(du))
                   + fmaf(0.5f, fabsf(v0 + v1), fabsf(dv));
    const float ix0 = fmaxf(px0, b.x0), ix1 = fminf(px1, b.x1);
    const float iy0 = fmaxf(py0, b.y0), iy1 = fminf(py1, b.y1);
    const float iwr = ix1 - ix0, ihr = iy1 - iy0;
    const float inter = fmaxf(iwr, 0.0f) * fmaxf(ihr, 0.0f);
    const float uni   = (parea + b.area) - inter;
    const float cw = (pw2 + du) - iwr;
    const float ch = (ph2 + dv) - ihr;
    const float carea = cw * ch;
    const float num = fmaf(uni, uni, inter * carea);
    const float mm  = num * __builtin_amdgcn_rcpf(uni * carea);
    return fmaf(-2.0f, mm, fmaf(5.0f, l1, fcp));
}

__global__ __launch_bounds__(NT)
void hungarian_cost_kernel(const float* __restrict__ logits,
                           const float* __restrict__ pboxes,
                           const int*   __restrict__ tlabels,
                           const float* __restrict__ tboxes,
                           float*       __restrict__ out,
                           int N, int M)
{
    const int t  = threadIdx.x;
    const int n0 = blockIdx.x * RPB;
    if (n0 >= N) return;
    const int rows = (N - n0 < RPB) ? (N - n0) : RPB;

    __shared__ float fc[RPB][NC];   // 2*focal+2, per row per class
    __shared__ float pp[RPB][8];    // px0,py0,px1,py1,parea,pw2,ph2,pad per row

    // ---- Prologue: focal costs + row params. ONE barrier. ----
#pragma unroll
    for (int r = 0; r < RPB; ++r) {
        if (r < rows) {
            const float x = logits[(size_t)(n0 + r) * NC + t];
            const float p = __builtin_amdgcn_rcpf(1.0f + __expf(-x));
            const float q = 1.0f - p;
            const float pos = ALPHAc * q * q * (-__logf(p + EPSc));
            const float neg = (1.0f - ALPHAc) * p * p * (-__logf(q + EPSc));
            fc[r][t] = fmaf(2.0f, pos - neg, 2.0f);
        }
    }
    if (t < rows) {
        const float4 pb = reinterpret_cast<const float4*>(pboxes)[n0 + t];
        pp[t][0] = fmaf(-0.5f, pb.z, pb.x);
        pp[t][1] = fmaf(-0.5f, pb.w, pb.y);
        pp[t][2] = fmaf( 0.5f, pb.z, pb.x);
        pp[t][3] = fmaf( 0.5f, pb.w, pb.y);
        pp[t][4] = pb.z * pb.w;
        pp[t][5] = pb.z + pb.z;
        pp[t][6] = pb.w + pb.w;
        pp[t][7] = 0.0f;
    }
    __syncthreads();

    const float4* tb4 = reinterpret_cast<const float4*>(tboxes);
    const float*  fc0 = &fc[0][0];

    // m-layout: nA float4 groups, nB float2 groups, scalar tail.
    // M=1600: 256*4 + 256*2 + 64*1.
    const int nA    = (M >> 2) < NT ? (M >> 2) : NT;
    const int baseB = 4 * nA;
    const int nB    = ((M - baseB) >> 1) < NT ? ((M - baseB) >> 1) : NT;
    const int baseC = baseB + 2 * nB;

    // ---- Phase A: 4 targets/thread, float4 stores. Only 4 TBoxes live. ----
    if (t < nA) {
        const int4 c4 = reinterpret_cast<const int4*>(tlabels)[t];
        const TBox b0 = make_box(tb4[4 * t + 0]);
        const TBox b1 = make_box(tb4[4 * t + 1]);
        const TBox b2 = make_box(tb4[4 * t + 2]);
        const TBox b3 = make_box(tb4[4 * t + 3]);
        const float* g0 = fc_base(fc0, c4.x);
        const float* g1 = fc_base(fc0, c4.y);
        const float* g2 = fc_base(fc0, c4.z);
        const float* g3 = fc_base(fc0, c4.w);
#pragma unroll
        for (int r = 0; r < RPB; ++r) {
            if (r >= rows) break;  // block-uniform
            const float4 p0 = *reinterpret_cast<const float4*>(&pp[r][0]);
            const float4 p1 = *reinterpret_cast<const float4*>(&pp[r][4]);
            const float f0 = g0[r * NC];
            const float f1 = g1[r * NC];
            const float f2 = g2[r * NC];
            const float f3 = g3[r * NC];
            f32x4 res;
            res.x = cost_elem(p0.x, p0.y, p0.z, p0.w, p1.x, p1.y, p1.z, b0, f0);
            res.y = cost_elem(p0.x, p0.y, p0.z, p0.w, p1.x, p1.y, p1.z, b1, f1);
            res.z = cost_elem(p0.x, p0.y, p0.z, p0.w, p1.x, p1.y, p1.z, b2, f2);
            res.w = cost_elem(p0.x, p0.y, p0.z, p0.w, p1.x, p1.y, p1.z, b3, f3);
            float* orow = out + (size_t)(n0 + r) * M;
            __builtin_nontemporal_store(res, reinterpret_cast<f32x4*>(orow) + t);
        }
    }

    // ---- Phase B: 2 targets/thread, float2 stores. ----
    if (t < nB) {
        const int2 c2 = reinterpret_cast<const int2*>(tlabels + baseB)[t];
        const TBox b0 = make_box(tb4[baseB + 2 * t + 0]);
        const TBox b1 = make_box(tb4[baseB + 2 * t + 1]);
        const float* g0 = fc_base(fc0, c2.x);
        const float* g1 = fc_base(fc0, c2.y);
#pragma unroll
        for (int r = 0; r < RPB; ++r) {
            if (r >= rows) break;
            const float4 p0 = *reinterpret_cast<const float4*>(&pp[r][0]);
            const float4 p1 = *reinterpret_cast<const float4*>(&pp[r][4]);
            const float f0 = g0[r * NC];
            const float f1 = g1[r * NC];
            f32x2 res;
            res.x = cost_elem(p0.x, p0.y, p0.z, p0.w, p1.x, p1.y, p1.z, b0, f0);
            res.y = cost_elem(p0.x, p0.y, p0.z, p0.w, p1.x, p1.y, p1.z, b1, f1);
            float* orow = out + (size_t)(n0 + r) * M + baseB;
            __builtin_nontemporal_store(res, reinterpret_cast<f32x2*>(orow) + t);
        }
    }

    // ---- Phase C: scalar tail (64 lanes for M=1600). ----
    for (int e = baseC + t; e < M; e += NT) {
        const TBox b = make_box(tb4[e]);
        const float* g = fc_base(fc0, tlabels[e]);
#pragma unroll
        for (int r = 0; r < RPB; ++r) {
            if (r >= rows) break;
            const float4 p0 = *reinterpret_cast<const float4*>(&pp[r][0]);
            const float4 p1 = *reinterpret_cast<const float4*>(&pp[r][4]);
            const float f = g[r * NC];
            const float v = cost_elem(p0.x, p0.y, p0.z, p0.w, p1.x, p1.y, p1.z, b, f);
            __builtin_nontemporal_store(v, out + (size_t)(n0 + r) * M + e);
        }
    }
}

extern "C" void kernel_launch(void* const* d_in, const int* in_sizes, int n_in,
                              void* d_out, int out_size, void* d_ws, size_t ws_size,
                              hipStream_t stream) {
    const float* logits  = (const float*)d_in[0];   // [16,1000,256] f32
    const float* pboxes  = (const float*)d_in[1];   // [16,1000,4]  f32
    const int*   tlabels = (const int*)d_in[2];     // [1600] i32
    const float* tboxes  = (const float*)d_in[3];   // [1600,4] f32

    float* out = (float*)d_out;

    const int N = in_sizes[1] / 4;   // 16000 pred rows
    const int M = in_sizes[2];       // 1600 targets

    const int nblocks = (N + RPB - 1) / RPB;   // 2000
    hipLaunchKernelGGL(hungarian_cost_kernel, dim3(nblocks), dim3(NT), 0, stream,
                       logits, pboxes, tlabels, tboxes, out, N, M);
}